// Round 6
// baseline (414.929 us; speedup 1.0000x reference)
//
#include <hip/hip_runtime.h>
#include <math.h>

#define N_TOK 16384
#define DM    4096
#define DH    2048
#define NE    64
#define TBK   32        // tokens per block
#define TOPK  4
#define KQ4   512       // k-range per wave (quarter of a model-half)
#define NSTEP 16        // KQ4 / 32

// out layout (all float32): topk_i [N,4] | topk_s [N,4] | scores [N,64] | aux_loss [1]
#define OFF_TI  0
#define OFF_TS  (N_TOK * TOPK)
#define OFF_SC  (N_TOK * TOPK * 2)
#define OFF_AUX (N_TOK * TOPK * 2 + N_TOK * NE)

typedef __attribute__((ext_vector_type(4)))  float  f32x4;
typedef __attribute__((ext_vector_type(16))) float  f32x16;
typedef __attribute__((ext_vector_type(8)))  __bf16 bf16x8;

// ws: __bf16 Bsplit fragment-major [h][ks64][split3][et2][sk2][lane64][8] (1.5 MB), then float esum[64]
#define BSPLIT_ELEMS (2 * 64 * 3 * 2 * 2 * 64 * 8)

__device__ __forceinline__ void split3(float a, __bf16& h, __bf16& m, __bf16& l) {
    h = (__bf16)a;                 // a = h+m+l EXACT (24 = 8+8+8 mantissa bits)
    float r = a - (float)h;
    m = (__bf16)r;
    float r2 = r - (float)m;
    l = (__bf16)r2;
}

// One thread per (h, ks, et, sk, lane): split 8 consecutive k of one expert column,
// write 3 bf16x8 fragments in MFMA-fragment-major order.
__global__ __launch_bounds__(256) void prep_B(
    const float* __restrict__ Ex, const float* __restrict__ Ey,
    __bf16* __restrict__ Bws)
{
    const int t    = blockIdx.x * 256 + threadIdx.x;   // 32768 threads
    const int lane = t & 63;
    const int sk   = (t >> 6) & 1;
    const int et   = (t >> 7) & 1;
    const int ks   = (t >> 8) & 63;
    const int h    = (t >> 14) & 1;
    const float* E = h ? Ey : Ex;
    const int e  = et * 32 + (lane & 31);
    const int k0 = ks * 32 + sk * 16 + (lane >> 5) * 8;
    bf16x8 vh, vm, vl;
    #pragma unroll
    for (int j = 0; j < 8; ++j) {
        __bf16 hh, mm, ll;
        split3(E[(size_t)(k0 + j) * NE + e], hh, mm, ll);
        vh[j] = hh; vm[j] = mm; vl[j] = ll;
    }
    #pragma unroll
    for (int s = 0; s < 3; ++s) {
        size_t base = ((((((size_t)h * 64 + ks) * 3 + s) * 2 + et) * 2 + sk) * 64 + lane) * 8;
        *(bf16x8*)(Bws + base) = (s == 0) ? vh : (s == 1) ? vm : vl;
    }
}

__global__ __launch_bounds__(512, 4) void torus_mfma(
    const float* __restrict__ u, const __bf16* __restrict__ Bws,
    const float* __restrict__ bias,
    const float* __restrict__ cp, const float* __restrict__ dp,
    const float* __restrict__ a1p, const float* __restrict__ b1p,
    float* __restrict__ out, float* __restrict__ esum)
{
    __shared__ float pre[4][NE][36];      // [h*2 + kq>>1][e][tok], pitch 36 (16B-aligned rows)
    __shared__ float stile[TBK][NE + 1];
    __shared__ float s_m[TBK], s_inv[TBK];

    const int tid  = threadIdx.x;
    const int t0   = blockIdx.x * TBK;
    const int lane = tid & 63;
    const int wv   = tid >> 6;            // 0..7
    const int h    = wv >> 2;             // model half (x / y)
    const int kq   = wv & 3;              // k-quarter within the model half
    const int lr   = lane & 31;           // MFMA A-row (token) / B-col (expert)
    const int lkh  = lane >> 5;           // k-subgroup within fragment

    const float* ap = u + (size_t)(t0 + lr) * DM + h * DH + kq * KQ4 + lkh * 8;
    const __bf16* bp0 = Bws + ((size_t)h * 64 + kq * 16) * 6144 + lane * 8;

    f32x16 acc[2][2] = {};                // [sk][et] independent chains; summed in epilogue
    f32x4  rA[2][4];                      // [buf][...] static-indexed 2-step A prefetch

    auto load_raw = [&](f32x4 (&r)[4], int s) {
        const float* p = ap + s * 32;
        r[0] = *(const f32x4*)(p);
        r[1] = *(const f32x4*)(p + 4);
        r[2] = *(const f32x4*)(p + 16);
        r[3] = *(const f32x4*)(p + 20);
    };

    auto step = [&](int s, f32x4 (&r)[4]) {
        // ---- 1) B loads FIRST (oldest in vmcnt order; L2-hot) ----
        const __bf16* bp = bp0 + (size_t)s * 6144;
        bf16x8 bh[2][2], bm[2][2], bl[2][2];
        #pragma unroll
        for (int et = 0; et < 2; ++et)
            #pragma unroll
            for (int sk = 0; sk < 2; ++sk) {
                bh[et][sk] = *(const bf16x8*)(bp + (0 * 4 + et * 2 + sk) * 512);
                bm[et][sk] = *(const bf16x8*)(bp + (1 * 4 + et * 2 + sk) * 512);
                bl[et][sk] = *(const bf16x8*)(bp + (2 * 4 + et * 2 + sk) * 512);
            }
        __builtin_amdgcn_sched_barrier(0);   // pin: B loads issued before anything below
        // ---- 2) split current A (VALU; covers B L2 latency) ----
        bf16x8 sh[2], sm[2], sl[2];
        #pragma unroll
        for (int sk = 0; sk < 2; ++sk)
            #pragma unroll
            for (int q = 0; q < 2; ++q)
                #pragma unroll
                for (int j = 0; j < 4; ++j) {
                    __bf16 hh, mm, ll;
                    split3(r[sk * 2 + q][j], hh, mm, ll);
                    sh[sk][q * 4 + j] = hh; sm[sk][q * 4 + j] = mm; sl[sk][q * 4 + j] = ll;
                }
        // ---- 3) A prefetch 2 steps ahead into the just-freed buffer (HBM) ----
        const int sp = (s + 2 < NSTEP) ? s + 2 : s;
        load_raw(r, sp);
        __builtin_amdgcn_sched_barrier(0);   // pin: split+prefetch stay above the MFMA block
        // ---- 4) MFMA: 6 exact products; consume bh -> bm -> bl ----
        #pragma unroll
        for (int et = 0; et < 2; ++et)
            #pragma unroll
            for (int sk = 0; sk < 2; ++sk) {
                acc[sk][et] = __builtin_amdgcn_mfma_f32_32x32x16_bf16(sh[sk], bh[et][sk], acc[sk][et], 0, 0, 0);
                acc[sk][et] = __builtin_amdgcn_mfma_f32_32x32x16_bf16(sm[sk], bh[et][sk], acc[sk][et], 0, 0, 0);
                acc[sk][et] = __builtin_amdgcn_mfma_f32_32x32x16_bf16(sl[sk], bh[et][sk], acc[sk][et], 0, 0, 0);
            }
        #pragma unroll
        for (int et = 0; et < 2; ++et)
            #pragma unroll
            for (int sk = 0; sk < 2; ++sk) {
                acc[sk][et] = __builtin_amdgcn_mfma_f32_32x32x16_bf16(sh[sk], bm[et][sk], acc[sk][et], 0, 0, 0);
                acc[sk][et] = __builtin_amdgcn_mfma_f32_32x32x16_bf16(sm[sk], bm[et][sk], acc[sk][et], 0, 0, 0);
            }
        #pragma unroll
        for (int et = 0; et < 2; ++et)
            #pragma unroll
            for (int sk = 0; sk < 2; ++sk)
                acc[sk][et] = __builtin_amdgcn_mfma_f32_32x32x16_bf16(sh[sk], bl[et][sk], acc[sk][et], 0, 0, 0);
        __builtin_amdgcn_sched_barrier(0);   // step boundary
    };

    load_raw(rA[0], 0);
    load_raw(rA[1], 1);
    #pragma unroll 1
    for (int s = 0; s < NSTEP; s += 2) {
        step(s,     rA[0]);
        step(s + 1, rA[1]);
    }

    // ---- combine: merge sk chains in regs, then kq partials two-stage in LDS ----
    // C/D layout: col=lane&31, row=(reg&3)+8*(reg>>2)+4*(lane>>5)
    const int slot = h * 2 + (kq >> 1);
    __syncthreads();
    if ((kq & 1) == 0) {
        #pragma unroll
        for (int et = 0; et < 2; ++et) {
            f32x16 a = acc[0][et] + acc[1][et];
            #pragma unroll
            for (int q = 0; q < 4; ++q) {
                int e  = et * 32 + lr;
                int tk = q * 8 + 4 * lkh;
                f32x4 v = { a[q*4+0], a[q*4+1], a[q*4+2], a[q*4+3] };
                *(f32x4*)&pre[slot][e][tk] = v;
            }
        }
    }
    __syncthreads();
    if ((kq & 1) == 1) {
        #pragma unroll
        for (int et = 0; et < 2; ++et) {
            f32x16 a = acc[0][et] + acc[1][et];
            #pragma unroll
            for (int q = 0; q < 4; ++q) {
                int e  = et * 32 + lr;
                int tk = q * 8 + 4 * lkh;
                f32x4 v = { a[q*4+0], a[q*4+1], a[q*4+2], a[q*4+3] };
                f32x4 o = *(f32x4*)&pre[slot][e][tk];
                v += o;
                *(f32x4*)&pre[slot][e][tk] = v;
            }
        }
    }
    __syncthreads();

    // ---- pointwise torus map: 512 threads x 4 (tok, e) each ----
    {
        const float c_ = *cp, d_ = *dp, a1_ = *a1p, b1_ = *b1p;
        const int tk = tid & 31;
        const int e0 = (tid >> 5) * 4;
        #pragma unroll
        for (int i = 0; i < 4; ++i) {
            int e = e0 + i;
            float x = pre[0][e][tk] + pre[1][e][tk];
            float y = pre[2][e][tk] + pre[3][e][tk];
            x = tanhf(x) * 2.0f; y = tanhf(y) * 2.0f;
            float xa = fabsf(x), ya = fabsf(y);
            float sc = (powf(xa, a1_) + powf(ya, b1_)) *
                       expf(-(powf(xa, c_) + powf(ya, d_))) + bias[e];
            stile[tk][e] = sc;
        }
    }
    __syncthreads();

    // ---- per-token top-4 + softmax denom ----
    if (tid < TBK) {
        const int t = tid;
        float bv[TOPK]; int bi[TOPK];
        #pragma unroll
        for (int p = 0; p < TOPK; ++p) {
            float best = -INFINITY; int besti = 0;
            for (int e = 0; e < NE; ++e) {
                float v = stile[t][e];
                bool taken = false;
                #pragma unroll
                for (int q = 0; q < p; ++q) taken = taken || (bi[q] == e);
                if (!taken && v > best) { best = v; besti = e; }  // strict > == lax.top_k tie-break
            }
            bv[p] = best; bi[p] = besti;
        }
        const float m = bv[0];
        float denom = 0.0f;
        for (int e = 0; e < NE; ++e) denom += expf(stile[t][e] - m);
        const float inv = 1.0f / denom;
        s_m[t] = m; s_inv[t] = inv;
        #pragma unroll
        for (int p = 0; p < TOPK; ++p) {
            out[OFF_TI + (size_t)(t0 + t) * TOPK + p] = (float)bi[p];
            out[OFF_TS + (size_t)(t0 + t) * TOPK + p] = bv[p];
        }
    }
    __syncthreads();

    // ---- per-expert prob column-sums -> global accumulate ----
    if (tid < NE) {
        const int e = tid;
        float cs = 0.0f;
        for (int t = 0; t < TBK; ++t)
            cs += expf(stile[t][e] - s_m[t]) * s_inv[t];
        atomicAdd(&esum[e], cs);
    }

    // ---- scores -> global, coalesced ----
    for (int idx = tid; idx < TBK * NE; idx += 512)
        out[OFF_SC + (size_t)t0 * NE + idx] = stile[idx >> 6][idx & (NE - 1)];
}

__global__ __launch_bounds__(64) void torus_aux(const float* __restrict__ esum,
                                                float* __restrict__ out)
{
    const int e = threadIdx.x;
    float s = esum[e] * (1.0f / (float)N_TOK);
    float v = s * s;
    #pragma unroll
    for (int off = 32; off > 0; off >>= 1) v += __shfl_down(v, off);
    if (e == 0) out[OFF_AUX] = v * (float)NE;
}

extern "C" void kernel_launch(void* const* d_in, const int* in_sizes, int n_in,
                              void* d_out, int out_size, void* d_ws, size_t ws_size,
                              hipStream_t stream) {
    const float* u    = (const float*)d_in[0];
    const float* Ex   = (const float*)d_in[1];
    const float* Ey   = (const float*)d_in[2];
    const float* bias = (const float*)d_in[3];
    const float* cp   = (const float*)d_in[4];
    const float* dp   = (const float*)d_in[5];
    const float* a1p  = (const float*)d_in[6];
    const float* b1p  = (const float*)d_in[7];
    float* out = (float*)d_out;
    __bf16* Bws = (__bf16*)d_ws;
    float* esum = (float*)((char*)d_ws + (size_t)BSPLIT_ELEMS * sizeof(__bf16));

    prep_B<<<128, 256, 0, stream>>>(Ex, Ey, Bws);
    hipMemsetAsync(esum, 0, NE * sizeof(float), stream);
    torus_mfma<<<N_TOK / TBK, 512, 0, stream>>>(u, Bws, bias, cp, dp, a1p, b1p, out, esum);
    torus_aux<<<1, 64, 0, stream>>>(esum, out);
}

// Round 7
// 131.742 us; speedup vs baseline: 3.1495x; 3.1495x over previous
//
#include <hip/hip_runtime.h>
#include <math.h>

#define N_TOK 16384
#define DM    4096
#define DH    2048
#define NE    64
#define TBK   32        // tokens per block
#define TOPK  4
#define KQ4   512       // k-range per wave (quarter of a model-half)
#define NSTEP 16        // KQ4 / 32

// out layout (all float32): topk_i [N,4] | topk_s [N,4] | scores [N,64] | aux_loss [1]
#define OFF_TI  0
#define OFF_TS  (N_TOK * TOPK)
#define OFF_SC  (N_TOK * TOPK * 2)
#define OFF_AUX (N_TOK * TOPK * 2 + N_TOK * NE)

typedef __attribute__((ext_vector_type(4)))  float  f32x4;
typedef __attribute__((ext_vector_type(16))) float  f32x16;
typedef __attribute__((ext_vector_type(8)))  __bf16 bf16x8;
typedef __attribute__((ext_vector_type(8)))  unsigned short u16x8;

// ws: __bf16 Bsplit fragment-major [h][ks64][split3][et2][sk2][lane64][8] (1.5 MB), then float esum[64]
#define BSPLIT_ELEMS (2 * 64 * 3 * 2 * 2 * 64 * 8)

__device__ __forceinline__ void split3(float a, __bf16& h, __bf16& m, __bf16& l) {
    h = (__bf16)a;                 // a = h+m+l EXACT (24 = 8+8+8 mantissa bits)
    float r = a - (float)h;
    m = (__bf16)r;
    float r2 = r - (float)m;
    l = (__bf16)r2;
}

// One thread per (h, ks, et, sk, lane): split 8 consecutive k of one expert column,
// write 3 bf16x8 fragments in MFMA-fragment-major order.
__global__ __launch_bounds__(256) void prep_B(
    const float* __restrict__ Ex, const float* __restrict__ Ey,
    __bf16* __restrict__ Bws)
{
    const int t    = blockIdx.x * 256 + threadIdx.x;   // 32768 threads
    const int lane = t & 63;
    const int sk   = (t >> 6) & 1;
    const int et   = (t >> 7) & 1;
    const int ks   = (t >> 8) & 63;
    const int h    = (t >> 14) & 1;
    const float* E = h ? Ey : Ex;
    const int e  = et * 32 + (lane & 31);
    const int k0 = ks * 32 + sk * 16 + (lane >> 5) * 8;
    bf16x8 vh, vm, vl;
    #pragma unroll
    for (int j = 0; j < 8; ++j) {
        __bf16 hh, mm, ll;
        split3(E[(size_t)(k0 + j) * NE + e], hh, mm, ll);
        vh[j] = hh; vm[j] = mm; vl[j] = ll;
    }
    #pragma unroll
    for (int s = 0; s < 3; ++s) {
        size_t base = ((((((size_t)h * 64 + ks) * 3 + s) * 2 + et) * 2 + sk) * 64 + lane) * 8;
        *(bf16x8*)(Bws + base) = (s == 0) ? vh : (s == 1) ? vm : vl;
    }
}

// NOTE: on this toolchain __launch_bounds__ 2nd arg behaves as min BLOCKS/CU
// (R6 evidence: (512,4) -> 64-VGPR cap + 811MB spills). (512,2) -> cap 128.
__global__ __launch_bounds__(512, 2) void torus_mfma(
    const float* __restrict__ u, const __bf16* __restrict__ Bws,
    const float* __restrict__ bias,
    const float* __restrict__ cp, const float* __restrict__ dp,
    const float* __restrict__ a1p, const float* __restrict__ b1p,
    float* __restrict__ out, float* __restrict__ esum)
{
    __shared__ float pre[4][NE][36];      // [h*2 + kq>>1][e][tok]
    __shared__ float stile[TBK][NE + 1];
    __shared__ float s_m[TBK], s_inv[TBK];

    const int tid  = threadIdx.x;
    const int t0   = blockIdx.x * TBK;
    const int lane = tid & 63;
    const int wv   = tid >> 6;            // 0..7
    const int h    = wv >> 2;             // model half (x / y)
    const int kq   = wv & 3;              // k-quarter within the model half
    const int lr   = lane & 31;           // MFMA A-row (token) / B-col (expert)
    const int lkh  = lane >> 5;           // k-subgroup within fragment

    const float* ap = u + (size_t)(t0 + lr) * DM + h * DH + kq * KQ4 + lkh * 8;
    const __bf16* bp0 = Bws + ((size_t)h * 64 + kq * 16) * 6144 + lane * 8;

    f32x16 acc[2][2] = {};                // [sk][et] independent chains; summed in epilogue
    f32x4  rA[2][4];                      // [buf][...] static-indexed 2-step A prefetch

    auto load_raw = [&](f32x4 (&r)[4], int s) {
        const float* p = ap + s * 32;
        r[0] = *(const f32x4*)(p);
        r[1] = *(const f32x4*)(p + 4);
        r[2] = *(const f32x4*)(p + 16);
        r[3] = *(const f32x4*)(p + 20);
    };

    auto step = [&](int s, f32x4 (&r)[4]) {
        // ---- 1) B loads FIRST (oldest in vmcnt order; L2-hot) ----
        const __bf16* bp = bp0 + (size_t)s * 6144;
        bf16x8 bh[2][2], bm[2][2], bl[2][2];
        #pragma unroll
        for (int et = 0; et < 2; ++et)
            #pragma unroll
            for (int sk = 0; sk < 2; ++sk) {
                bh[et][sk] = *(const bf16x8*)(bp + (0 * 4 + et * 2 + sk) * 512);
                bm[et][sk] = *(const bf16x8*)(bp + (1 * 4 + et * 2 + sk) * 512);
                bl[et][sk] = *(const bf16x8*)(bp + (2 * 4 + et * 2 + sk) * 512);
            }
        __builtin_amdgcn_sched_barrier(0);   // pin: B loads issued before anything below
        // ---- 2) exact mask-based A split (pure and/sub/perm; no cvt chain) ----
        // h32 = a & 0xFFFF0000 (exact bf16 via truncation, low 16 bits zero);
        // r = a - h32 exact; m32 = r & mask; r2 = r - m32 has <=8 significand
        // bits -> its fp32 low 16 bits are zero -> bf16 = top 16 bits, exact.
        u16x8 sh[2], sm[2], sl[2];
        #pragma unroll
        for (int sk = 0; sk < 2; ++sk)
            #pragma unroll
            for (int q = 0; q < 2; ++q)
                #pragma unroll
                for (int j = 0; j < 4; ++j) {
                    float a = r[sk * 2 + q][j];
                    unsigned h32 = __float_as_uint(a) & 0xFFFF0000u;
                    float rr = a - __uint_as_float(h32);
                    unsigned m32 = __float_as_uint(rr) & 0xFFFF0000u;
                    float r2 = rr - __uint_as_float(m32);
                    sh[sk][q * 4 + j] = (unsigned short)(h32 >> 16);
                    sm[sk][q * 4 + j] = (unsigned short)(m32 >> 16);
                    sl[sk][q * 4 + j] = (unsigned short)(__float_as_uint(r2) >> 16);
                }
        // ---- 3) A prefetch 2 steps ahead into the just-freed buffer (HBM) ----
        const int sp = (s + 2 < NSTEP) ? s + 2 : s;
        load_raw(r, sp);
        __builtin_amdgcn_sched_barrier(0);   // pin: split+prefetch stay above the MFMA block
        // ---- 4) MFMA: 6 exact products; consume bh -> bm -> bl ----
        #pragma unroll
        for (int et = 0; et < 2; ++et)
            #pragma unroll
            for (int sk = 0; sk < 2; ++sk) {
                bf16x8 vh_ = __builtin_bit_cast(bf16x8, sh[sk]);
                bf16x8 vm_ = __builtin_bit_cast(bf16x8, sm[sk]);
                bf16x8 vl_ = __builtin_bit_cast(bf16x8, sl[sk]);
                acc[sk][et] = __builtin_amdgcn_mfma_f32_32x32x16_bf16(vh_, bh[et][sk], acc[sk][et], 0, 0, 0);
                acc[sk][et] = __builtin_amdgcn_mfma_f32_32x32x16_bf16(vm_, bh[et][sk], acc[sk][et], 0, 0, 0);
                acc[sk][et] = __builtin_amdgcn_mfma_f32_32x32x16_bf16(vl_, bh[et][sk], acc[sk][et], 0, 0, 0);
            }
        #pragma unroll
        for (int et = 0; et < 2; ++et)
            #pragma unroll
            for (int sk = 0; sk < 2; ++sk) {
                bf16x8 vh_ = __builtin_bit_cast(bf16x8, sh[sk]);
                bf16x8 vm_ = __builtin_bit_cast(bf16x8, sm[sk]);
                acc[sk][et] = __builtin_amdgcn_mfma_f32_32x32x16_bf16(vh_, bm[et][sk], acc[sk][et], 0, 0, 0);
                acc[sk][et] = __builtin_amdgcn_mfma_f32_32x32x16_bf16(vm_, bm[et][sk], acc[sk][et], 0, 0, 0);
            }
        #pragma unroll
        for (int et = 0; et < 2; ++et)
            #pragma unroll
            for (int sk = 0; sk < 2; ++sk) {
                bf16x8 vh_ = __builtin_bit_cast(bf16x8, sh[sk]);
                acc[sk][et] = __builtin_amdgcn_mfma_f32_32x32x16_bf16(vh_, bl[et][sk], acc[sk][et], 0, 0, 0);
            }
        __builtin_amdgcn_sched_barrier(0);   // step boundary
    };

    load_raw(rA[0], 0);
    load_raw(rA[1], 1);
    #pragma unroll 1
    for (int s = 0; s < NSTEP; s += 2) {
        step(s,     rA[0]);
        step(s + 1, rA[1]);
    }

    // ---- combine: merge sk chains in regs, then kq partials two-stage in LDS ----
    // C/D layout: col=lane&31, row=(reg&3)+8*(reg>>2)+4*(lane>>5)
    const int slot = h * 2 + (kq >> 1);
    __syncthreads();
    if ((kq & 1) == 0) {
        #pragma unroll
        for (int et = 0; et < 2; ++et) {
            f32x16 a = acc[0][et] + acc[1][et];
            #pragma unroll
            for (int q = 0; q < 4; ++q) {
                int e  = et * 32 + lr;
                int tk = q * 8 + 4 * lkh;
                f32x4 v = { a[q*4+0], a[q*4+1], a[q*4+2], a[q*4+3] };
                *(f32x4*)&pre[slot][e][tk] = v;
            }
        }
    }
    __syncthreads();
    if ((kq & 1) == 1) {
        #pragma unroll
        for (int et = 0; et < 2; ++et) {
            f32x16 a = acc[0][et] + acc[1][et];
            #pragma unroll
            for (int q = 0; q < 4; ++q) {
                int e  = et * 32 + lr;
                int tk = q * 8 + 4 * lkh;
                f32x4 v = { a[q*4+0], a[q*4+1], a[q*4+2], a[q*4+3] };
                f32x4 o = *(f32x4*)&pre[slot][e][tk];
                v += o;
                *(f32x4*)&pre[slot][e][tk] = v;
            }
        }
    }
    __syncthreads();

    // ---- pointwise torus map: 512 threads x 4 (tok, e) each ----
    {
        const float c_ = *cp, d_ = *dp, a1_ = *a1p, b1_ = *b1p;
        const int tk = tid & 31;
        const int e0 = (tid >> 5) * 4;
        #pragma unroll
        for (int i = 0; i < 4; ++i) {
            int e = e0 + i;
            float x = pre[0][e][tk] + pre[1][e][tk];
            float y = pre[2][e][tk] + pre[3][e][tk];
            x = tanhf(x) * 2.0f; y = tanhf(y) * 2.0f;
            float xa = fabsf(x), ya = fabsf(y);
            float sc = (powf(xa, a1_) + powf(ya, b1_)) *
                       expf(-(powf(xa, c_) + powf(ya, d_))) + bias[e];
            stile[tk][e] = sc;
        }
    }
    __syncthreads();

    // ---- per-token top-4 + softmax denom ----
    if (tid < TBK) {
        const int t = tid;
        float bv[TOPK]; int bi[TOPK];
        #pragma unroll
        for (int p = 0; p < TOPK; ++p) {
            float best = -INFINITY; int besti = 0;
            for (int e = 0; e < NE; ++e) {
                float v = stile[t][e];
                bool taken = false;
                #pragma unroll
                for (int q = 0; q < p; ++q) taken = taken || (bi[q] == e);
                if (!taken && v > best) { best = v; besti = e; }  // strict > == lax.top_k tie-break
            }
            bv[p] = best; bi[p] = besti;
        }
        const float m = bv[0];
        float denom = 0.0f;
        for (int e = 0; e < NE; ++e) denom += expf(stile[t][e] - m);
        const float inv = 1.0f / denom;
        s_m[t] = m; s_inv[t] = inv;
        #pragma unroll
        for (int p = 0; p < TOPK; ++p) {
            out[OFF_TI + (size_t)(t0 + t) * TOPK + p] = (float)bi[p];
            out[OFF_TS + (size_t)(t0 + t) * TOPK + p] = bv[p];
        }
    }
    __syncthreads();

    // ---- per-expert prob column-sums -> global accumulate ----
    if (tid < NE) {
        const int e = tid;
        float cs = 0.0f;
        for (int t = 0; t < TBK; ++t)
            cs += expf(stile[t][e] - s_m[t]) * s_inv[t];
        atomicAdd(&esum[e], cs);
    }

    // ---- scores -> global, coalesced ----
    for (int idx = tid; idx < TBK * NE; idx += 512)
        out[OFF_SC + (size_t)t0 * NE + idx] = stile[idx >> 6][idx & (NE - 1)];
}

__global__ __launch_bounds__(64) void torus_aux(const float* __restrict__ esum,
                                                float* __restrict__ out)
{
    const int e = threadIdx.x;
    float s = esum[e] * (1.0f / (float)N_TOK);
    float v = s * s;
    #pragma unroll
    for (int off = 32; off > 0; off >>= 1) v += __shfl_down(v, off);
    if (e == 0) out[OFF_AUX] = v * (float)NE;
}

extern "C" void kernel_launch(void* const* d_in, const int* in_sizes, int n_in,
                              void* d_out, int out_size, void* d_ws, size_t ws_size,
                              hipStream_t stream) {
    const float* u    = (const float*)d_in[0];
    const float* Ex   = (const float*)d_in[1];
    const float* Ey   = (const float*)d_in[2];
    const float* bias = (const float*)d_in[3];
    const float* cp   = (const float*)d_in[4];
    const float* dp   = (const float*)d_in[5];
    const float* a1p  = (const float*)d_in[6];
    const float* b1p  = (const float*)d_in[7];
    float* out = (float*)d_out;
    __bf16* Bws = (__bf16*)d_ws;
    float* esum = (float*)((char*)d_ws + (size_t)BSPLIT_ELEMS * sizeof(__bf16));

    prep_B<<<128, 256, 0, stream>>>(Ex, Ey, Bws);
    hipMemsetAsync(esum, 0, NE * sizeof(float), stream);
    torus_mfma<<<N_TOK / TBK, 512, 0, stream>>>(u, Bws, bias, cp, dp, a1p, b1p, out, esum);
    torus_aux<<<1, 64, 0, stream>>>(esum, out);
}

// Round 8
// 109.227 us; speedup vs baseline: 3.7988x; 1.2061x over previous
//
#include <hip/hip_runtime.h>
#include <math.h>
#include <stdint.h>

#define N_TOK 16384
#define DM    4096
#define DH    2048
#define NE    64
#define TBK   32        // tokens per block
#define TOPK  4
#define KQ    1024      // k-range per wave (half of a model-half)
#define NSTEP 32        // KQ / 32

// out layout (all float32): topk_i [N,4] | topk_s [N,4] | scores [N,64] | aux_loss [1]
#define OFF_TI  0
#define OFF_TS  (N_TOK * TOPK)
#define OFF_SC  (N_TOK * TOPK * 2)
#define OFF_AUX (N_TOK * TOPK * 2 + N_TOK * NE)

typedef __attribute__((ext_vector_type(4)))  float  f32x4;
typedef __attribute__((ext_vector_type(16))) float  f32x16;
typedef __attribute__((ext_vector_type(8)))  __bf16 bf16x8;
typedef __attribute__((ext_vector_type(8)))  unsigned short u16x8;

// ws: __bf16 Bsplit fragment-major [h][ks64][split3][et2][sk2][lane64][8] (1.5 MB), then float esum[64]
#define BSPLIT_ELEMS (2 * 64 * 3 * 2 * 2 * 64 * 8)

__device__ __forceinline__ void split3(float a, __bf16& h, __bf16& m, __bf16& l) {
    h = (__bf16)a;                 // a = h+m+l EXACT (24 = 8+8+8 mantissa bits)
    float r = a - (float)h;
    m = (__bf16)r;
    float r2 = r - (float)m;
    l = (__bf16)r2;
}

// async global->LDS, 16B per lane; LDS dest = wave-uniform base + lane*16
__device__ __forceinline__ void stage16(const float* g, void* l) {
    __builtin_amdgcn_global_load_lds(
        (const __attribute__((address_space(1))) unsigned int*)(uintptr_t)g,
        (__attribute__((address_space(3))) unsigned int*)(uintptr_t)l,
        16, 0, 0);
}

// One thread per (h, ks, et, sk, lane): split 8 consecutive k of one expert column,
// write 3 bf16x8 fragments in MFMA-fragment-major order.
__global__ __launch_bounds__(256) void prep_B(
    const float* __restrict__ Ex, const float* __restrict__ Ey,
    __bf16* __restrict__ Bws)
{
    const int t    = blockIdx.x * 256 + threadIdx.x;   // 32768 threads
    const int lane = t & 63;
    const int sk   = (t >> 6) & 1;
    const int et   = (t >> 7) & 1;
    const int ks   = (t >> 8) & 63;
    const int h    = (t >> 14) & 1;
    const float* E = h ? Ey : Ex;
    const int e  = et * 32 + (lane & 31);
    const int k0 = ks * 32 + sk * 16 + (lane >> 5) * 8;
    bf16x8 vh, vm, vl;
    #pragma unroll
    for (int j = 0; j < 8; ++j) {
        __bf16 hh, mm, ll;
        split3(E[(size_t)(k0 + j) * NE + e], hh, mm, ll);
        vh[j] = hh; vm[j] = mm; vl[j] = ll;
    }
    #pragma unroll
    for (int s = 0; s < 3; ++s) {
        size_t base = ((((((size_t)h * 64 + ks) * 3 + s) * 2 + et) * 2 + sk) * 64 + lane) * 8;
        *(bf16x8*)(Bws + base) = (s == 0) ? vh : (s == 1) ? vm : vl;
    }
}

__global__ __launch_bounds__(256, 2) void torus_mfma(
    const float* __restrict__ u, const __bf16* __restrict__ Bws,
    const float* __restrict__ bias,
    const float* __restrict__ cp, const float* __restrict__ dp,
    const float* __restrict__ a1p, const float* __restrict__ b1p,
    float* __restrict__ out, float* __restrict__ esum)
{
    // 64 KB: [0..64K) = 4 waves x (4-deep ring x 4 KB). Epilogue aliases the front.
    __shared__ __align__(16) unsigned char smem[65536];

    const int tid  = threadIdx.x;
    const int t0   = blockIdx.x * TBK;
    const int lane = tid & 63;
    const int wv   = tid >> 6;            // 0..3
    const int h    = wv >> 1;             // model half (x / y)
    const int kh   = wv & 1;              // k-half within the model half
    const int lr   = lane & 31;           // MFMA A-row (token) / B-col (expert)
    const int lkh  = lane >> 5;           // k-subgroup within fragment

    float* ring = (float*)(smem + wv * 16384);

    // ---- A staging: per-lane PRE-SWIZZLED global source (rule #21: swizzle both sides) ----
    // issue i covers rows i*8..i*8+7; lane slot = (row = i*8 + (lane>>3), phys chunk = lane&7).
    // phys chunk c holds logical chunk c ^ (row&7)  ->  source chunk = (lane&7) ^ (lane>>3).
    const int   srow  = lane >> 3;
    const int   schk  = (lane & 7) ^ srow;
    const float* gbase = u + (size_t)(t0 + srow) * DM + h * DH + kh * KQ + schk * 4;

    auto stage = [&](int s) {
        const float* g = gbase + s * 32;
        unsigned char* lb = (unsigned char*)ring + (s & 3) * 4096;
        #pragma unroll
        for (int i = 0; i < 4; ++i)
            stage16(g + (size_t)i * 8 * DM, lb + i * 1024);
    };

    // ---- A read addresses: logical chunks {2lkh, 2lkh+1, 4+2lkh, 5+2lkh}, phys = log ^ (lr&7)
    int rb[4];
    {
        const int ch0 = 2 * lkh, ch1 = 2 * lkh + 1, ch2 = 4 + 2 * lkh, ch3 = 5 + 2 * lkh;
        rb[0] = lr * 32 + ((ch0 ^ (lr & 7)) * 4);
        rb[1] = lr * 32 + ((ch1 ^ (lr & 7)) * 4);
        rb[2] = lr * 32 + ((ch2 ^ (lr & 7)) * 4);
        rb[3] = lr * 32 + ((ch3 ^ (lr & 7)) * 4);
    }

    // ---- B: fragment-major split workspace, prefetch one step ahead ----
    const __bf16* bp0 = Bws + ((size_t)h * 64 + kh * 32) * 6144 + lane * 8;
    auto loadB = [&](bf16x8 (&b)[12], int s) {
        const __bf16* bp = bp0 + (size_t)s * 6144;
        #pragma unroll
        for (int et = 0; et < 2; ++et)
            #pragma unroll
            for (int sk = 0; sk < 2; ++sk) {
                b[0 + et * 2 + sk] = *(const bf16x8*)(bp + (0 + et * 2 + sk) * 512);
                b[4 + et * 2 + sk] = *(const bf16x8*)(bp + (4 + et * 2 + sk) * 512);
                b[8 + et * 2 + sk] = *(const bf16x8*)(bp + (8 + et * 2 + sk) * 512);
            }
    };

    f32x16 acc[2][2] = {};                // [sk][et] independent chains

    auto body = [&](int s, bf16x8 (&bu)[12], bf16x8 (&bn)[12]) {
        const int sn = (s + 1 < NSTEP) ? s + 1 : s;
        loadB(bn, sn);                       // B(s+1): L2, retires behind older stages
        if (s + 3 < NSTEP) stage(s + 3);     // A(s+3): HBM, deep prefetch, no VGPR cost
        __builtin_amdgcn_sched_barrier(0);
        // ensure stage(s) landed (prologue case; steady state: <=36 outstanding = no-op)
        asm volatile("s_waitcnt vmcnt(36)" ::: "memory");
        __builtin_amdgcn_sched_barrier(0);
        const float* rp = ring + (s & 3) * 1024;
        f32x4 r0 = *(const f32x4*)(rp + rb[0]);
        f32x4 r1 = *(const f32x4*)(rp + rb[1]);
        f32x4 r2 = *(const f32x4*)(rp + rb[2]);
        f32x4 r3 = *(const f32x4*)(rp + rb[3]);
        // exact mask-based split: h = a&0xFFFF0000 (exact); r=a-h; m=r&mask; l=r-m (exact)
        u16x8 sh[2], sm[2], sl[2];
        #pragma unroll
        for (int q = 0; q < 2; ++q)
            #pragma unroll
            for (int j = 0; j < 4; ++j) {
                {
                    float a = (q == 0 ? r0 : r1)[j];
                    unsigned h32 = __float_as_uint(a) & 0xFFFF0000u;
                    float rr = a - __uint_as_float(h32);
                    unsigned m32 = __float_as_uint(rr) & 0xFFFF0000u;
                    float r2f = rr - __uint_as_float(m32);
                    sh[0][q * 4 + j] = (unsigned short)(h32 >> 16);
                    sm[0][q * 4 + j] = (unsigned short)(m32 >> 16);
                    sl[0][q * 4 + j] = (unsigned short)(__float_as_uint(r2f) >> 16);
                }
                {
                    float a = (q == 0 ? r2 : r3)[j];
                    unsigned h32 = __float_as_uint(a) & 0xFFFF0000u;
                    float rr = a - __uint_as_float(h32);
                    unsigned m32 = __float_as_uint(rr) & 0xFFFF0000u;
                    float r2f = rr - __uint_as_float(m32);
                    sh[1][q * 4 + j] = (unsigned short)(h32 >> 16);
                    sm[1][q * 4 + j] = (unsigned short)(m32 >> 16);
                    sl[1][q * 4 + j] = (unsigned short)(__float_as_uint(r2f) >> 16);
                }
            }
        __builtin_amdgcn_sched_barrier(0);
        // 6 exact products; consume bh -> bm -> bl
        #pragma unroll
        for (int et = 0; et < 2; ++et)
            #pragma unroll
            for (int sk = 0; sk < 2; ++sk) {
                bf16x8 vh_ = __builtin_bit_cast(bf16x8, sh[sk]);
                bf16x8 vm_ = __builtin_bit_cast(bf16x8, sm[sk]);
                bf16x8 vl_ = __builtin_bit_cast(bf16x8, sl[sk]);
                acc[sk][et] = __builtin_amdgcn_mfma_f32_32x32x16_bf16(vh_, bu[0 + et * 2 + sk], acc[sk][et], 0, 0, 0);
                acc[sk][et] = __builtin_amdgcn_mfma_f32_32x32x16_bf16(vm_, bu[0 + et * 2 + sk], acc[sk][et], 0, 0, 0);
                acc[sk][et] = __builtin_amdgcn_mfma_f32_32x32x16_bf16(vl_, bu[0 + et * 2 + sk], acc[sk][et], 0, 0, 0);
            }
        #pragma unroll
        for (int et = 0; et < 2; ++et)
            #pragma unroll
            for (int sk = 0; sk < 2; ++sk) {
                bf16x8 vh_ = __builtin_bit_cast(bf16x8, sh[sk]);
                bf16x8 vm_ = __builtin_bit_cast(bf16x8, sm[sk]);
                acc[sk][et] = __builtin_amdgcn_mfma_f32_32x32x16_bf16(vh_, bu[4 + et * 2 + sk], acc[sk][et], 0, 0, 0);
                acc[sk][et] = __builtin_amdgcn_mfma_f32_32x32x16_bf16(vm_, bu[4 + et * 2 + sk], acc[sk][et], 0, 0, 0);
            }
        #pragma unroll
        for (int et = 0; et < 2; ++et)
            #pragma unroll
            for (int sk = 0; sk < 2; ++sk) {
                bf16x8 vh_ = __builtin_bit_cast(bf16x8, sh[sk]);
                acc[sk][et] = __builtin_amdgcn_mfma_f32_32x32x16_bf16(vh_, bu[8 + et * 2 + sk], acc[sk][et], 0, 0, 0);
            }
        __builtin_amdgcn_sched_barrier(0);
    };

    // prologue: 3-deep A stage + B(0)
    stage(0); stage(1); stage(2);
    bf16x8 b0[12], b1[12];
    loadB(b0, 0);
    #pragma unroll 1
    for (int s = 0; s < NSTEP; s += 2) {
        body(s,     b0, b1);
        body(s + 1, b1, b0);
    }

    // ---- epilogue (aliases ring LDS; all waves past K-loop first) ----
    __syncthreads();
    float (*pre)[NE][36]   = (float(*)[NE][36])smem;               // [2][64][36]
    float (*stile)[NE + 1] = (float(*)[NE + 1])(smem + 18432);     // [32][65]
    float* s_m  = (float*)(smem + 18432 + 8320);
    float* s_inv = s_m + TBK;

    // C/D layout: col=lane&31, row=(reg&3)+8*(reg>>2)+4*(lane>>5)
    if (kh == 0) {
        #pragma unroll
        for (int et = 0; et < 2; ++et) {
            f32x16 a = acc[0][et] + acc[1][et];
            #pragma unroll
            for (int q = 0; q < 4; ++q) {
                int e  = et * 32 + lr;
                int tk = q * 8 + 4 * lkh;
                f32x4 v = { a[q*4+0], a[q*4+1], a[q*4+2], a[q*4+3] };
                *(f32x4*)&pre[h][e][tk] = v;
            }
        }
    }
    __syncthreads();
    if (kh == 1) {
        #pragma unroll
        for (int et = 0; et < 2; ++et) {
            f32x16 a = acc[0][et] + acc[1][et];
            #pragma unroll
            for (int q = 0; q < 4; ++q) {
                int e  = et * 32 + lr;
                int tk = q * 8 + 4 * lkh;
                f32x4 v = { a[q*4+0], a[q*4+1], a[q*4+2], a[q*4+3] };
                f32x4 o = *(f32x4*)&pre[h][e][tk];
                v += o;
                *(f32x4*)&pre[h][e][tk] = v;
            }
        }
    }
    __syncthreads();

    // ---- pointwise torus map: 256 threads x 8 (tok, e) each ----
    {
        const float c_ = *cp, d_ = *dp, a1_ = *a1p, b1_ = *b1p;
        const int tk = tid & 31;
        const int e0 = (tid >> 5) * 8;
        #pragma unroll
        for (int i = 0; i < 8; ++i) {
            int e = e0 + i;
            float x = pre[0][e][tk];
            float y = pre[1][e][tk];
            x = tanhf(x) * 2.0f; y = tanhf(y) * 2.0f;
            float xa = fabsf(x), ya = fabsf(y);
            float sc = (powf(xa, a1_) + powf(ya, b1_)) *
                       expf(-(powf(xa, c_) + powf(ya, d_))) + bias[e];
            stile[tk][e] = sc;
        }
    }
    __syncthreads();

    // ---- per-token top-4 + softmax denom ----
    if (tid < TBK) {
        const int t = tid;
        float bv[TOPK]; int bi[TOPK];
        #pragma unroll
        for (int p = 0; p < TOPK; ++p) {
            float best = -INFINITY; int besti = 0;
            for (int e = 0; e < NE; ++e) {
                float v = stile[t][e];
                bool taken = false;
                #pragma unroll
                for (int q = 0; q < p; ++q) taken = taken || (bi[q] == e);
                if (!taken && v > best) { best = v; besti = e; }  // strict > == lax.top_k tie-break
            }
            bv[p] = best; bi[p] = besti;
        }
        const float m = bv[0];
        float denom = 0.0f;
        for (int e = 0; e < NE; ++e) denom += expf(stile[t][e] - m);
        const float inv = 1.0f / denom;
        s_m[t] = m; s_inv[t] = inv;
        #pragma unroll
        for (int p = 0; p < TOPK; ++p) {
            out[OFF_TI + (size_t)(t0 + t) * TOPK + p] = (float)bi[p];
            out[OFF_TS + (size_t)(t0 + t) * TOPK + p] = bv[p];
        }
    }
    __syncthreads();

    // ---- per-expert prob column-sums -> global accumulate ----
    if (tid < NE) {
        const int e = tid;
        float cs = 0.0f;
        for (int t = 0; t < TBK; ++t)
            cs += expf(stile[t][e] - s_m[t]) * s_inv[t];
        atomicAdd(&esum[e], cs);
    }

    // ---- scores -> global, coalesced ----
    for (int idx = tid; idx < TBK * NE; idx += 256)
        out[OFF_SC + (size_t)t0 * NE + idx] = stile[idx >> 6][idx & (NE - 1)];
}

__global__ __launch_bounds__(64) void torus_aux(const float* __restrict__ esum,
                                                float* __restrict__ out)
{
    const int e = threadIdx.x;
    float s = esum[e] * (1.0f / (float)N_TOK);
    float v = s * s;
    #pragma unroll
    for (int off = 32; off > 0; off >>= 1) v += __shfl_down(v, off);
    if (e == 0) out[OFF_AUX] = v * (float)NE;
}

extern "C" void kernel_launch(void* const* d_in, const int* in_sizes, int n_in,
                              void* d_out, int out_size, void* d_ws, size_t ws_size,
                              hipStream_t stream) {
    const float* u    = (const float*)d_in[0];
    const float* Ex   = (const float*)d_in[1];
    const float* Ey   = (const float*)d_in[2];
    const float* bias = (const float*)d_in[3];
    const float* cp   = (const float*)d_in[4];
    const float* dp   = (const float*)d_in[5];
    const float* a1p  = (const float*)d_in[6];
    const float* b1p  = (const float*)d_in[7];
    float* out = (float*)d_out;
    __bf16* Bws = (__bf16*)d_ws;
    float* esum = (float*)((char*)d_ws + (size_t)BSPLIT_ELEMS * sizeof(__bf16));

    prep_B<<<128, 256, 0, stream>>>(Ex, Ey, Bws);
    hipMemsetAsync(esum, 0, NE * sizeof(float), stream);
    torus_mfma<<<N_TOK / TBK, 256, 0, stream>>>(u, Bws, bias, cp, dp, a1p, b1p, out, esum);
    torus_aux<<<1, 64, 0, stream>>>(esum, out);
}